// Round 4
// baseline (159.087 us; speedup 1.0000x reference)
//
#include <hip/hip_runtime.h>
#include <math.h>

// Problem constants (fixed by the reference)
#define BB 128
#define SS 512
#define FF 16
#define VV 200000
#define TT 17

// ---------------------------------------------------------------------------
// Kernel 1: emissions[b,s,t] = sum_f emb[input_seq[b,s,f], t]
// One thread per (pos, t) output element. Adjacent lanes have consecutive t
// within the same row -> wave-loads coalesce within emb rows instead of
// touching 64 scattered lines. 17408 waves of latency hiding.
// ---------------------------------------------------------------------------
__global__ __launch_bounds__(256) void emissions_kernel(
    const int* __restrict__ seq, const float* __restrict__ emb,
    float* __restrict__ em_out)
{
    int gid = blockIdx.x * 256 + threadIdx.x;
    if (gid >= BB * SS * TT) return;
    int pos = gid / TT;              // compiler magic-mul
    int t   = gid - pos * TT;

    const int* idx = seq + (size_t)pos * FF;
    int v[FF];
#pragma unroll
    for (int f = 0; f < FF; ++f) v[f] = idx[f];

    float s0 = 0.f, s1 = 0.f, s2 = 0.f, s3 = 0.f;
#pragma unroll
    for (int f = 0; f < FF; f += 4) {
        s0 += emb[(size_t)v[f + 0] * TT + t];
        s1 += emb[(size_t)v[f + 1] * TT + t];
        s2 += emb[(size_t)v[f + 2] * TT + t];
        s3 += emb[(size_t)v[f + 3] * TT + t];
    }
    em_out[gid] = (s0 + s1) + (s2 + s3);
}

// ---------------------------------------------------------------------------
// Kernel 2: per-batch CRF numerator + forward pass (log Z), one wave / batch.
// Linear-space recursion A'[j] = (sum_i A[i]*exp(trans[i][j])) * exp(em[s][j])
// Broadcasts of A via __shfl (ds_bpermute, VGPR->VGPR: no VALU->SGPR->VALU
// hazard that readlane incurred). 8-deep register prefetch ring for em; exact
// pow2 renorm once per 8-chunk. mask is all-true in this problem.
// Result accumulated into d_out via one float atomic per batch (out pre-zeroed
// by hipMemsetAsync in kernel_launch).
// ---------------------------------------------------------------------------
__global__ __launch_bounds__(64) void crf_kernel(
    const int* __restrict__ tags,
    const float* __restrict__ start_t,
    const float* __restrict__ end_t,
    const float* __restrict__ trans,
    const float* __restrict__ em,
    float* __restrict__ out)
{
    const int b = blockIdx.x;
    const int lane = threadIdx.x;
    const int* tg = tags + b * SS;
    const float* e = em + (size_t)b * SS * TT;

    // ---- numerator score: parallel over s, butterfly reduce ----
    float partial = 0.f;
    for (int s = 1 + lane; s < SS; s += 64) {
        int tp = tg[s - 1], tc = tg[s];
        partial += trans[tp * TT + tc] + e[s * TT + tc];
    }
#pragma unroll
    for (int off = 32; off > 0; off >>= 1)
        partial += __shfl_xor(partial, off);

    // ---- forward recursion in linear space on lanes 0..16 ----
    const int j = (lane < TT) ? lane : (lane - TT);  // shadow lanes harmless
    float et[TT];
#pragma unroll
    for (int i = 0; i < TT; ++i) et[i] = __expf(trans[i * TT + j]);

    float A    = __expf(start_t[j] + e[j]);   // s = 0
    float logC = 0.f;

    // prefetch ring: xb[u] = em[s_pending + u][j]
    float xb[8];
#pragma unroll
    for (int u = 0; u < 8; ++u) xb[u] = e[(1 + u) * TT + j];

    // matvec: 17 pipelined ds_bpermute broadcasts, then fma tree
#define MATVEC_STEP(Xval)                                    \
    {                                                        \
        float bb[TT];                                        \
        _Pragma("unroll")                                    \
        for (int i = 0; i < TT; ++i) bb[i] = __shfl(A, i);   \
        float s0 = 0.f, s1 = 0.f, s2 = 0.f, s3 = 0.f;        \
        _Pragma("unroll")                                    \
        for (int i = 0; i < 16; i += 4) {                    \
            s0 += bb[i + 0] * et[i + 0];                     \
            s1 += bb[i + 1] * et[i + 1];                     \
            s2 += bb[i + 2] * et[i + 2];                     \
            s3 += bb[i + 3] * et[i + 3];                     \
        }                                                    \
        s0 += bb[16] * et[16];                               \
        A = ((s0 + s1) + (s2 + s3)) * (Xval);                \
    }

    // main: 63 chunks of 8 steps -> s = 1 .. 504
    int s = 1;
    for (int c = 0; c < 63; ++c) {
#pragma unroll
        for (int u = 0; u < 8; ++u) {
            float X = __expf(xb[u]);
            int sn = s + u + 8;               // scalar index math
            if (sn > SS - 1) sn = SS - 1;     // clamp keeps loads in-bounds
            xb[u] = e[sn * TT + j];           // refill ring, 8 steps ahead
            MATVEC_STEP(X);
        }
        s += 8;
        // exact pow2 renorm, off the log/exp path
        float r = __shfl(A, 0);               // positive normal
        int eb = (int)((__float_as_uint(r) >> 23) & 0xFF);
        logC += (float)(eb - 127) * 0.6931471805599453f;
        A *= __uint_as_float((unsigned)(254 - eb) << 23);
    }

    // remainder: s = 505 .. 511 (7 steps), xb[0..6] already hold them
#pragma unroll
    for (int u = 0; u < 7; ++u) {
        float X = __expf(xb[u]);
        MATVEC_STEP(X);
    }
#undef MATVEC_STEP

    // ---- log_z = logC + log(sum_j A[j] * exp(end[j])) ----
    float v = (lane < TT) ? A * __expf(end_t[j]) : 0.f;
#pragma unroll
    for (int off = 32; off > 0; off >>= 1)
        v += __shfl_xor(v, off);

    if (lane == 0) {
        float log_z = logC + __logf(v);
        int t0 = tg[0], tl = tg[SS - 1];
        float score = partial + start_t[t0] + e[t0] + end_t[tl];
        atomicAdd(out, (score - log_z) * (1.0f / BB));
    }
}

extern "C" void kernel_launch(void* const* d_in, const int* in_sizes, int n_in,
                              void* d_out, int out_size, void* d_ws, size_t ws_size,
                              hipStream_t stream)
{
    const int*   seq     = (const int*)d_in[0];     // (B,S,F) int32
    const int*   tags    = (const int*)d_in[1];     // (B,S)   int32
    // d_in[2] = mask — all ones in this problem; unused.
    const float* emb     = (const float*)d_in[3];   // (V,T)   f32
    const float* start_t = (const float*)d_in[4];   // (T,)
    const float* end_t   = (const float*)d_in[5];   // (T,)
    const float* trans   = (const float*)d_in[6];   // (T,T)

    float* em = (float*)d_ws;                       // B*S*T floats = 4.25 MB

    hipMemsetAsync(d_out, 0, sizeof(float), stream);
    int n_em = BB * SS * TT;
    emissions_kernel<<<(n_em + 255) / 256, 256, 0, stream>>>(seq, emb, em);
    crf_kernel<<<BB, 64, 0, stream>>>(tags, start_t, end_t, trans, em,
                                      (float*)d_out);
}